// Round 1
// baseline (501.791 us; speedup 1.0000x reference)
//
#include <hip/hip_runtime.h>

#define NB   32
#define NQL  2048
#define NKL  2048
#define DH   128
#define QBLK 64
#define KBLK 64
#define EPS  1e-6f

typedef __bf16 bf16x8 __attribute__((ext_vector_type(8)));
typedef float  f32x4  __attribute__((ext_vector_type(4)));

static __device__ __forceinline__ unsigned short f2bf(float f) {
    union { float f; unsigned u; } x; x.f = f;
    unsigned r = x.u + 0x7FFFu + ((x.u >> 16) & 1u);   // RNE
    return (unsigned short)(r >> 16);
}

union BF8 { unsigned short u[8]; bf16x8 v; };

// One block = one (batch, 64-row Q tile). 4 waves; wave w owns q rows [w*16, w*16+16).
// Swapped QK^T: S^T = K·Q^T so lane l&15 = q, softmax state is lane-local in k.
__global__ __launch_bounds__(256) void
attn_kernel(const float* __restrict__ Qg, const float* __restrict__ Kg,
            const float* __restrict__ Vg, const float* __restrict__ Mg,
            float* __restrict__ Og)
{
    // XCD swizzle: 1024 wgs, 8 XCDs -> each XCD gets 4 whole batches (K/V L2 reuse)
    const int wg = ((blockIdx.x & 7) << 7) | (blockIdx.x >> 3);
    const int b  = wg >> 5;
    const int q0 = (wg & 31) * QBLK;

    const int t  = threadIdx.x;
    const int w  = t >> 6;     // wave 0..3
    const int l  = t & 63;
    const int lq = l & 15;     // q within wave strip (S^T layout) / N-dim lane index
    const int lg = l >> 4;     // lane group 0..3

    __shared__ unsigned short Ks[KBLK][136];   // [k][d] bf16, +8 pad
    __shared__ unsigned short Vs[DH][72];      // [d][k] bf16 (transposed), +8 pad
    __shared__ unsigned short Ps[4][16][72];   // per-wave P[q][k] bf16, +8 pad

    const int qrow = q0 + w * 16 + lq;

    // Q fragments (B-operand layout: lane holds Q[qrow][c*32 + lg*8 + j], j=0..7)
    bf16x8 qf[4];
    {
        const float* qb = Qg + ((size_t)b * NQL + qrow) * DH;
        #pragma unroll
        for (int c = 0; c < 4; ++c) {
            const float* p = qb + c * 32 + lg * 8;
            float4 x = *(const float4*)(p);
            float4 y = *(const float4*)(p + 4);
            BF8 u;
            u.u[0]=f2bf(x.x); u.u[1]=f2bf(x.y); u.u[2]=f2bf(x.z); u.u[3]=f2bf(x.w);
            u.u[4]=f2bf(y.x); u.u[5]=f2bf(y.y); u.u[6]=f2bf(y.z); u.u[7]=f2bf(y.w);
            qf[c] = u.v;
        }
    }

    float m_run = -1e30f, z_part = 0.f, s_part = 0.f;
    f32x4 oacc[8];
    #pragma unroll
    for (int n = 0; n < 8; ++n) oacc[n] = (f32x4){0.f, 0.f, 0.f, 0.f};

    const int   trow  = t >> 2;        // K staging: row 0..63
    const int   tc4   = (t & 3) * 4;   // K staging: 16B sub-chunk
    const float scale = 0.08838834764831845f;  // 1/sqrt(128)

    for (int kt = 0; kt < NKL / KBLK; ++kt) {
        const int k0 = kt * KBLK;

        // mask prefetch (global only; overlaps staging + QK^T)
        // lane needs mask[qrow][k0 + m*16 + lg*4 + r]
        float mkf[4][4];
        {
            const float* mb = Mg + ((size_t)b * NQL + qrow) * NKL + k0;
            #pragma unroll
            for (int m = 0; m < 4; ++m) {
                float4 x = *(const float4*)(mb + m * 16 + lg * 4);
                mkf[m][0]=x.x; mkf[m][1]=x.y; mkf[m][2]=x.z; mkf[m][3]=x.w;
            }
        }

        __syncthreads();   // prev tile's LDS reads complete before restage

        // stage K tile -> Ks[k][d]
        {
            const float* kb = Kg + ((size_t)b * NKL + k0 + trow) * DH;
            #pragma unroll
            for (int i = 0; i < 8; ++i) {
                const int col = i * 16 + tc4;
                float4 x = *(const float4*)(kb + col);
                ushort4 h = make_ushort4(f2bf(x.x), f2bf(x.y), f2bf(x.z), f2bf(x.w));
                *(ushort4*)&Ks[trow][col] = h;
            }
        }
        // stage V tile transposed -> Vs[d][k] via per-thread 4x4 blocks
        {
            #pragma unroll
            for (int it = 0; it < 2; ++it) {
                const int idx = it * 256 + t;
                const int db = idx & 31, kb4 = idx >> 5;
                const float* vb = Vg + ((size_t)b * NKL + k0 + kb4 * 4) * DH + db * 4;
                float r0[4], r1[4], r2[4], r3[4];
                { float4 x=*(const float4*)(vb        ); r0[0]=x.x; r0[1]=x.y; r0[2]=x.z; r0[3]=x.w; }
                { float4 x=*(const float4*)(vb +   DH ); r1[0]=x.x; r1[1]=x.y; r1[2]=x.z; r1[3]=x.w; }
                { float4 x=*(const float4*)(vb + 2*DH ); r2[0]=x.x; r2[1]=x.y; r2[2]=x.z; r2[3]=x.w; }
                { float4 x=*(const float4*)(vb + 3*DH ); r3[0]=x.x; r3[1]=x.y; r3[2]=x.z; r3[3]=x.w; }
                #pragma unroll
                for (int j = 0; j < 4; ++j) {
                    ushort4 h = make_ushort4(f2bf(r0[j]), f2bf(r1[j]), f2bf(r2[j]), f2bf(r3[j]));
                    *(ushort4*)&Vs[db * 4 + j][kb4 * 4] = h;
                }
            }
        }
        __syncthreads();

        // S^T = K · Q^T : wave computes 64k x 16q; frag m: k rows m*16..m*16+15
        // D layout: col = lq = q, row = lg*4 + r = k (within m-tile)
        f32x4 sacc[4];
        #pragma unroll
        for (int m = 0; m < 4; ++m) sacc[m] = (f32x4){0.f, 0.f, 0.f, 0.f};
        #pragma unroll
        for (int m = 0; m < 4; ++m) {
            #pragma unroll
            for (int c = 0; c < 4; ++c) {
                bf16x8 af = *(bf16x8*)&Ks[m * 16 + lq][c * 32 + lg * 8];
                sacc[m] = __builtin_amdgcn_mfma_f32_16x16x32_bf16(af, qf[c], sacc[m], 0, 0, 0);
            }
        }

        // online softmax: lane owns 16 scores of q=qrow at k = k0 + m*16 + lg*4 + r
        float sv[4][4], tmax = -1e30f;
        #pragma unroll
        for (int m = 0; m < 4; ++m)
            #pragma unroll
            for (int r = 0; r < 4; ++r) {
                sv[m][r] = sacc[m][r] * scale;
                tmax = fmaxf(tmax, sv[m][r]);
            }
        tmax = fmaxf(tmax, __shfl_xor(tmax, 16));
        tmax = fmaxf(tmax, __shfl_xor(tmax, 32));
        const float mnew  = fmaxf(m_run, tmax);
        const float alpha = __expf(m_run - mnew);
        m_run = mnew;

        float zl = 0.f, sl = 0.f, pm[4][4];
        #pragma unroll
        for (int m = 0; m < 4; ++m)
            #pragma unroll
            for (int r = 0; r < 4; ++r) {
                float p  = __expf(sv[m][r] - mnew);
                zl += p;
                float pq = p * mkf[m][r];
                sl += pq;
                pm[m][r] = pq;
            }
        z_part = z_part * alpha + zl;   // partial over this lane's k-subset
        s_part = s_part * alpha + sl;

        // P -> LDS: lane packs 4 consecutive k (fixed q) per frag -> b64 write
        #pragma unroll
        for (int m = 0; m < 4; ++m) {
            ushort4 h = make_ushort4(f2bf(pm[m][0]), f2bf(pm[m][1]),
                                     f2bf(pm[m][2]), f2bf(pm[m][3]));
            *(ushort4*)&Ps[w][lq][m * 16 + lg * 4] = h;
        }

        // rescale O by alpha(q); O rows are q = lg*4 + r -> fetch via shfl
        float alr[4];
        #pragma unroll
        for (int r = 0; r < 4; ++r) alr[r] = __shfl(alpha, lg * 4 + r);
        #pragma unroll
        for (int n = 0; n < 8; ++n)
            #pragma unroll
            for (int r = 0; r < 4; ++r) oacc[n][r] *= alr[r];

        // O += P · V : A = P[q][k] (row=lq), B = Vs[d][k] col-read (col=lq)
        #pragma unroll
        for (int kc = 0; kc < 2; ++kc) {
            bf16x8 pa = *(bf16x8*)&Ps[w][lq][kc * 32 + lg * 8];
            #pragma unroll
            for (int n = 0; n < 8; ++n) {
                bf16x8 vv = *(bf16x8*)&Vs[n * 16 + lq][kc * 32 + lg * 8];
                oacc[n] = __builtin_amdgcn_mfma_f32_16x16x32_bf16(pa, vv, oacc[n], 0, 0, 0);
            }
        }
    }

    // epilogue: finish cross-lane Z/S reduction, divide, store
    float z = z_part + __shfl_xor(z_part, 16);
    z += __shfl_xor(z, 32);
    float s = s_part + __shfl_xor(s_part, 16);
    s += __shfl_xor(s, 32);
    const float inv = 1.f / (s + EPS * z);
    float ivr[4];
    #pragma unroll
    for (int r = 0; r < 4; ++r) ivr[r] = __shfl(inv, lg * 4 + r);

    float* ob = Og + ((size_t)b * NQL + q0 + w * 16) * DH;
    #pragma unroll
    for (int n = 0; n < 8; ++n)
        #pragma unroll
        for (int r = 0; r < 4; ++r)
            ob[(size_t)(lg * 4 + r) * DH + n * 16 + lq] = oacc[n][r] * ivr[r];
}

extern "C" void kernel_launch(void* const* d_in, const int* in_sizes, int n_in,
                              void* d_out, int out_size, void* d_ws, size_t ws_size,
                              hipStream_t stream)
{
    const float* Q = (const float*)d_in[0];
    const float* K = (const float*)d_in[1];
    const float* V = (const float*)d_in[2];
    const float* M = (const float*)d_in[3];
    float* O = (float*)d_out;
    dim3 grid(NB * (NQL / QBLK));   // 1024
    attn_kernel<<<grid, 256, 0, stream>>>(Q, K, V, M, O);
}